// Round 7
// baseline (227.501 us; speedup 1.0000x reference)
//
#include <hip/hip_runtime.h>
#include <hip/hip_bf16.h>
#include <math.h>
#include <limits.h>

// Problem constants (fixed by setup_inputs: B=8, M=1024, D=256, H=W=100)
#define BATCH 8
#define MQ    1024
#define DIM   256
#define NHEAD 8
#define NPTS  4
#define NPROJ 98            // 64 offsets + 32 attn logits + 2 base-ref
#define NCORN (NHEAD * NPTS * 4)   // 128 corner samples per row
#define GRIDW 32            // dedupe grid (32x32 pixels)

typedef __attribute__((ext_vector_type(8))) short  short8;  // 8 bf16 = 4 VGPR
typedef __attribute__((ext_vector_type(4))) float  f32x4;

static __device__ __forceinline__ ushort f2bf(float f) {
    union { float f; unsigned u; } v; v.f = f;
    const unsigned r = v.u + 0x7fffu + ((v.u >> 16) & 1u);   // round-nearest-even
    return (ushort)(r >> 16);
}

// ---------------------------------------------------------------------------
// Kernel A: fused projections + softmax + bilinear sample + weighted agg.
// One block per (b, m) row. 256 threads = 4 corner-groups x 64 float4 lanes.
// NEW phase 2.5: dedupe the 128 corner gathers into ~40-60 distinct pixels
// (points cluster within a few px) via an LDS weight grid -> cuts the
// L2/L3-side gather traffic ~2.5x, which the R6 arithmetic says is the limit.
// ---------------------------------------------------------------------------
__global__ __launch_bounds__(256) void fused_sample_kernel(
    const float* __restrict__ SADQ,   // [B, M, D]
    const float* __restrict__ E,      // [B, H*W, D]
    const float* __restrict__ Wo, const float* __restrict__ bo,   // [D,64],[64]
    const float* __restrict__ Wa, const float* __restrict__ ba,   // [D,32],[32]
    const float* __restrict__ Wr, const float* __restrict__ br,   // [D,2],[2]
    const int*   __restrict__ Hp, const int* __restrict__ Wdp,    // scalars
    ushort* __restrict__ aggb)        // [B*M, D] bf16
{
    const int row = blockIdx.x;       // b*MQ + m
    const int b   = row / MQ;
    const int tid = threadIdx.x;

    __shared__ float  qs[DIM];
    __shared__ float  proj[128];      // [0,64) offsets, [64,96) logits, [96,98) base
    __shared__ float  partial[128];   // upper-half d partial sums
    __shared__ float  sW[NCORN];
    __shared__ int    sIdx[NCORN];    // pixel index in float4 units (pix*64)
    __shared__ float4 red[4][64];     // cross-corner-group reduction
    __shared__ float  grid[GRIDW * GRIDW];   // dedupe weight grid
    __shared__ float  sWd[NCORN];     // compacted weights
    __shared__ int    sIdxd[NCORN];   // compacted pixel idx (float4 units)
    __shared__ int    sBBox[4];       // xmin, ymin, xmax, ymax
    __shared__ int    sCnt;

    qs[tid] = SADQ[(size_t)row * DIM + tid];
    // init dedupe state (runs before the phase-1 sync)
    if (tid == 0) {
        sBBox[0] = INT_MAX; sBBox[1] = INT_MAX;
        sBBox[2] = INT_MIN; sBBox[3] = INT_MIN;
        sCnt = 0;
    }
    #pragma unroll
    for (int c = tid; c < GRIDW * GRIDW; c += 256) grid[c] = 0.f;
    __syncthreads();

    // ---- Phase 1: projections. Output j computed by two threads (d halves).
    {
        const int j    = tid & 127;
        const int half = tid >> 7;
        float s = 0.f, bias = 0.f;
        if (j < NPROJ) {
            const float* Wb; int col, ncols;
            if (j < 64)      { Wb = Wo; col = j;      ncols = 64; bias = bo[col]; }
            else if (j < 96) { Wb = Wa; col = j - 64; ncols = 32; bias = ba[col]; }
            else             { Wb = Wr; col = j - 96; ncols = 2;  bias = br[col]; }
            const float* wp = Wb + (size_t)(half * 128) * ncols + col;
            const float* qp = qs + half * 128;
            #pragma unroll 8
            for (int d = 0; d < 128; ++d)
                s = fmaf(qp[d], wp[(size_t)d * ncols], s);
        }
        if (half) partial[j] = s;
        __syncthreads();
        if (!half && j < NPROJ) proj[j] = s + bias + partial[j];
        __syncthreads();
    }

    // ---- Phase 2: softmax over each head's 4 points + per-point corner setup.
    const int Hh = *Hp;
    const int Ww = *Wdp;
    if (tid < NHEAD * NPTS) {
        const int p = tid;            // linear (h*4 + pt)
        const int h = p >> 2;
        const float l0 = proj[64 + h * 4 + 0];
        const float l1 = proj[64 + h * 4 + 1];
        const float l2 = proj[64 + h * 4 + 2];
        const float l3 = proj[64 + h * 4 + 3];
        const float mx = fmaxf(fmaxf(l0, l1), fmaxf(l2, l3));
        const float e0 = expf(l0 - mx), e1 = expf(l1 - mx),
                    e2 = expf(l2 - mx), e3 = expf(l3 - mx);
        const float inv = 1.f / (e0 + e1 + e2 + e3);
        const float aw  = expf(proj[64 + p] - mx) * inv * (1.f / NHEAD);

        const float lx = proj[96] + 0.1f * proj[p * 2 + 0];
        const float ly = proj[97] + 0.1f * proj[p * 2 + 1];
        const float ix = ((lx + 1.f) * (float)Ww - 1.f) * 0.5f;
        const float iy = ((ly + 1.f) * (float)Hh - 1.f) * 0.5f;
        const float x0f = floorf(ix), y0f = floorf(iy);
        const int   x0  = (int)x0f,   y0  = (int)y0f;
        const float wx1 = ix - x0f, wx0 = 1.f - wx1;
        const float wy1 = iy - y0f, wy0 = 1.f - wy1;

        #pragma unroll
        for (int c = 0; c < 4; ++c) {
            const int   xc = x0 + (c & 1);
            const int   yc = y0 + (c >> 1);
            const float wx = (c & 1) ? wx1 : wx0;
            const float wy = (c >> 1) ? wy1 : wy0;
            const bool valid = (xc >= 0) && (xc < Ww) && (yc >= 0) && (yc < Hh);
            const int xi = min(max(xc, 0), Ww - 1);
            const int yi = min(max(yc, 0), Hh - 1);
            sW  [p * 4 + c] = valid ? (wx * wy * aw) : 0.f;
            sIdx[p * 4 + c] = (yi * Ww + xi) * (DIM / 4);   // float4 units
        }
    }
    __syncthreads();

    // ---- Phase 2.5a: bbox of nonzero-weight corner pixels.
    if (tid < NCORN) {
        const float w = sW[tid];
        if (w > 0.f) {
            const int pix = sIdx[tid] >> 6;
            const int x = pix % Ww;
            const int y = pix / Ww;
            atomicMin(&sBBox[0], x); atomicMin(&sBBox[1], y);
            atomicMax(&sBBox[2], x); atomicMax(&sBBox[3], y);
        }
    }
    __syncthreads();

    const int xmin = sBBox[0], ymin = sBBox[1];
    const bool fits = (xmin != INT_MAX) &&
                      (sBBox[2] - xmin < GRIDW) && (sBBox[3] - ymin < GRIDW);

    if (fits) {
        // ---- Phase 2.5b: scatter-add weights into the pixel grid.
        if (tid < NCORN) {
            const float w = sW[tid];
            if (w > 0.f) {
                const int pix = sIdx[tid] >> 6;
                const int x = pix % Ww;
                const int y = pix / Ww;
                atomicAdd(&grid[(y - ymin) * GRIDW + (x - xmin)], w);
            }
        }
        __syncthreads();
        // ---- Phase 2.5c: compact nonzero cells.
        for (int c = tid; c < GRIDW * GRIDW; c += 256) {
            const float w = grid[c];
            if (w != 0.f) {
                const int pos = atomicAdd(&sCnt, 1);
                const int x = xmin + (c & (GRIDW - 1));
                const int y = ymin + (c >> 5);
                sWd[pos]   = w;
                sIdxd[pos] = (y * Ww + x) * (DIM / 4);
            }
        }
        __syncthreads();
    }

    // ---- Phase 3: gather + weighted accumulate.
    const int cg  = tid >> 6;
    const int ch4 = tid & 63;
    const float4* __restrict__ Eb4 =
        (const float4*)(E + (size_t)b * (size_t)(Hh * Ww) * DIM);

    float4 acc = make_float4(0.f, 0.f, 0.f, 0.f);
    if (fits) {
        const int n = sCnt;
        for (int i = cg; i < n; i += 4) {
            const float w   = sWd[i];
            const int   idx = sIdxd[i];
            const float4 e  = Eb4[(size_t)idx + ch4];
            acc.x = fmaf(w, e.x, acc.x);
            acc.y = fmaf(w, e.y, acc.y);
            acc.z = fmaf(w, e.z, acc.z);
            acc.w = fmaf(w, e.w, acc.w);
        }
    } else {
        #pragma unroll 8
        for (int t = 0; t < 32; ++t) {
            const int   i   = cg * 32 + t;
            const float w   = sW[i];
            const int   idx = sIdx[i];
            const float4 e  = Eb4[(size_t)idx + ch4];
            acc.x = fmaf(w, e.x, acc.x);
            acc.y = fmaf(w, e.y, acc.y);
            acc.z = fmaf(w, e.z, acc.z);
            acc.w = fmaf(w, e.w, acc.w);
        }
    }
    red[cg][ch4] = acc;
    __syncthreads();

    if (cg == 0) {
        const float4 r0 = red[0][ch4];
        const float4 r1 = red[1][ch4];
        const float4 r2 = red[2][ch4];
        const float4 r3 = red[3][ch4];
        ushort4 o;
        o.x = f2bf((r0.x + r1.x) + (r2.x + r3.x));
        o.y = f2bf((r0.y + r1.y) + (r2.y + r3.y));
        o.z = f2bf((r0.z + r1.z) + (r2.z + r3.z));
        o.w = f2bf((r0.w + r1.w) + (r2.w + r3.w));
        *(ushort4*)&aggb[(size_t)row * DIM + ch4 * 4] = o;
    }
}

// ---------------------------------------------------------------------------
// Tiny kernel: WpT[n][k] = bf16(Wp[k][n]).  (unchanged)
// ---------------------------------------------------------------------------
__global__ __launch_bounds__(256) void wp_convert_kernel(
    const float* __restrict__ Wp, ushort* __restrict__ WpT)
{
    const int k = blockIdx.x;
    const int n = threadIdx.x;
    WpT[(size_t)n * DIM + k] = f2bf(Wp[(size_t)k * DIM + n]);
}

// ---------------------------------------------------------------------------
// Kernel B: out = agg @ Wp + bp via bf16 MFMA (fp32 accumulate). (unchanged)
// ---------------------------------------------------------------------------
__global__ __launch_bounds__(256) void mfma_gemm_kernel(
    const ushort* __restrict__ A,     // [M, 256] bf16
    const ushort* __restrict__ BT,    // [256, 256] bf16 (transposed Wp)
    const float*  __restrict__ bp,    // [256]
    float* __restrict__ out)          // [M, 256]
{
    __shared__ ushort ldsA[64 * 40];
    __shared__ ushort ldsB[64 * 40];

    const int tid  = threadIdx.x;
    const int mb   = blockIdx.x * 64;
    const int nb   = blockIdx.y * 64;
    const int wave = tid >> 6;
    const int lane = tid & 63;
    const int r0   = (wave >> 1) * 32;
    const int c0   = (wave & 1) * 32;
    const int lrow = lane & 15;
    const int kgrp = lane >> 4;

    const int sm = tid >> 2;
    const int sc = (tid & 3) * 8;

    f32x4 acc00 = {0.f, 0.f, 0.f, 0.f};
    f32x4 acc01 = {0.f, 0.f, 0.f, 0.f};
    f32x4 acc10 = {0.f, 0.f, 0.f, 0.f};
    f32x4 acc11 = {0.f, 0.f, 0.f, 0.f};

    for (int kb = 0; kb < DIM; kb += 32) {
        *(uint4*)&ldsA[sm * 40 + sc] =
            *(const uint4*)&A[(size_t)(mb + sm) * DIM + kb + sc];
        *(uint4*)&ldsB[sm * 40 + sc] =
            *(const uint4*)&BT[(size_t)(nb + sm) * DIM + kb + sc];
        __syncthreads();

        const short8 a0 = *(const short8*)&ldsA[(r0 + lrow)      * 40 + kgrp * 8];
        const short8 a1 = *(const short8*)&ldsA[(r0 + 16 + lrow) * 40 + kgrp * 8];
        const short8 b0 = *(const short8*)&ldsB[(c0 + lrow)      * 40 + kgrp * 8];
        const short8 b1 = *(const short8*)&ldsB[(c0 + 16 + lrow) * 40 + kgrp * 8];

        acc00 = __builtin_amdgcn_mfma_f32_16x16x32_bf16(a0, b0, acc00, 0, 0, 0);
        acc01 = __builtin_amdgcn_mfma_f32_16x16x32_bf16(a0, b1, acc01, 0, 0, 0);
        acc10 = __builtin_amdgcn_mfma_f32_16x16x32_bf16(a1, b0, acc10, 0, 0, 0);
        acc11 = __builtin_amdgcn_mfma_f32_16x16x32_bf16(a1, b1, acc11, 0, 0, 0);
        __syncthreads();
    }

    const int orow = mb + r0 + kgrp * 4;
    const int ocol = nb + c0 + lrow;
    const float bp0 = bp[ocol];
    const float bp1 = bp[ocol + 16];
    #pragma unroll
    for (int reg = 0; reg < 4; ++reg) {
        out[(size_t)(orow + reg)      * DIM + ocol]      = acc00[reg] + bp0;
        out[(size_t)(orow + reg)      * DIM + ocol + 16] = acc01[reg] + bp1;
        out[(size_t)(orow + 16 + reg) * DIM + ocol]      = acc10[reg] + bp0;
        out[(size_t)(orow + 16 + reg) * DIM + ocol + 16] = acc11[reg] + bp1;
    }
}

// ---------------------------------------------------------------------------
extern "C" void kernel_launch(void* const* d_in, const int* in_sizes, int n_in,
                              void* d_out, int out_size, void* d_ws, size_t ws_size,
                              hipStream_t stream)
{
    const float* SADQ = (const float*)d_in[0];
    const float* E    = (const float*)d_in[1];
    const float* Wo   = (const float*)d_in[2];
    const float* bo   = (const float*)d_in[3];
    const float* Wa   = (const float*)d_in[4];
    const float* ba   = (const float*)d_in[5];
    const float* Wr   = (const float*)d_in[6];
    const float* br   = (const float*)d_in[7];
    const float* Wp   = (const float*)d_in[8];
    const float* bp   = (const float*)d_in[9];
    const int*   Hp   = (const int*)d_in[10];
    const int*   Wdp  = (const int*)d_in[11];

    const int BM = in_sizes[0] / DIM;          // 8192 rows

    ushort* aggb = (ushort*)d_ws;                                 // 4 MB bf16
    ushort* WpT  = (ushort*)((char*)d_ws + (size_t)BM * DIM * 2); // 128 KB
    float*  out  = (float*)d_out;

    fused_sample_kernel<<<BM, 256, 0, stream>>>(
        SADQ, E, Wo, bo, Wa, ba, Wr, br, Hp, Wdp, aggb);

    wp_convert_kernel<<<DIM, 256, 0, stream>>>(Wp, WpT);

    dim3 g2(BM / 64, DIM / 64);
    mfma_gemm_kernel<<<g2, 256, 0, stream>>>(aggb, WpT, bp, out);
}

// Round 9
// 217.349 us; speedup vs baseline: 1.0467x; 1.0467x over previous
//
#include <hip/hip_runtime.h>
#include <hip/hip_bf16.h>
#include <math.h>

// Problem constants (fixed by setup_inputs: B=8, M=1024, D=256, H=W=100)
#define BATCH 8
#define MQ    1024
#define DIM   256
#define NHEAD 8
#define NPTS  4
#define NPROJ 98            // 64 offsets + 32 attn logits + 2 base-ref
#define PSTR  112           // padded projection row stride (floats)

typedef __attribute__((ext_vector_type(8))) short  short8;  // 8 bf16 = 4 VGPR
typedef __attribute__((ext_vector_type(4))) float  f32x4;

static __device__ __forceinline__ ushort f2bf(float f) {
    union { float f; unsigned u; } v; v.f = f;
    const unsigned r = v.u + 0x7fffu + ((v.u >> 16) & 1u);   // round-nearest-even
    return (ushort)(r >> 16);
}

// Per-scalar liveness hammer (float4 "+v" is a tied indirect constraint ->
// unsupported on gfx950; scalar floats are single VGPRs and compile fine).
#define KEEP4(v) asm volatile("" : "+v"(v.x), "+v"(v.y), "+v"(v.z), "+v"(v.w))

// ---------------------------------------------------------------------------
// Build Wcat[256][112] = [Wo | Wa | Wr | 0-pad] and bcat[112] (once, ~1 us).
// ---------------------------------------------------------------------------
__global__ __launch_bounds__(112) void wcat_build_kernel(
    const float* __restrict__ Wo, const float* __restrict__ bo,
    const float* __restrict__ Wa, const float* __restrict__ ba,
    const float* __restrict__ Wr, const float* __restrict__ br,
    float* __restrict__ Wcat, float* __restrict__ bcat)
{
    const int k = blockIdx.x;      // 0..255
    const int j = threadIdx.x;     // 0..111
    float w = 0.f, bias = 0.f;
    if (j < 64)      { w = Wo[k * 64 + j];        bias = bo[j]; }
    else if (j < 96) { w = Wa[k * 32 + (j - 64)]; bias = ba[j - 64]; }
    else if (j < 98) { w = Wr[k * 2  + (j - 96)]; bias = br[j - 96]; }
    Wcat[k * PSTR + j] = w;
    if (k == 0) bcat[j] = bias;
}

// ---------------------------------------------------------------------------
// Projection GEMM (fp32): P[8192][112] = SADQ @ Wcat + bcat.
// 256 blocks x 256 threads; block = 32 rows; thread = 2 rows x 7 cols.
// fp32 is required: bf16 offsets would shift sample positions ~0.15px ->
// output error above the 1.875e-2 threshold.
// ---------------------------------------------------------------------------
__global__ __launch_bounds__(256) void proj_kernel(
    const float* __restrict__ SADQ,   // [BM, 256]
    const float* __restrict__ Wcat,   // [256, 112]
    const float* __restrict__ bcat,   // [112]
    float* __restrict__ P)            // [BM, 112]
{
    __shared__ float Qs[32][65];      // +1 pad: q-read banks differ per row
    __shared__ float Ws[64][112];

    const int tid  = threadIdx.x;
    const int row0 = blockIdx.x * 32;
    const int rg   = tid >> 4;        // 0..15 (2 rows each)
    const int cg   = tid & 15;        // 0..15 (7 cols each)

    float acc0[7] = {};
    float acc1[7] = {};

    for (int kc = 0; kc < DIM; kc += 64) {
        #pragma unroll
        for (int i = 0; i < 2; ++i) {
            const int fi = tid * 2 + i;            // 0..511
            const int r  = fi >> 4;
            const int k4 = (fi & 15) * 4;
            const float4 v = *(const float4*)&SADQ[(size_t)(row0 + r) * DIM + kc + k4];
            Qs[r][k4 + 0] = v.x; Qs[r][k4 + 1] = v.y;
            Qs[r][k4 + 2] = v.z; Qs[r][k4 + 3] = v.w;
        }
        for (int fi = tid; fi < 64 * 28; fi += 256) {   // 28 float4 per k-row
            const int k  = fi / 28;
            const int j4 = (fi % 28) * 4;
            *(float4*)&Ws[k][j4] = *(const float4*)&Wcat[(size_t)(kc + k) * PSTR + j4];
        }
        __syncthreads();

        #pragma unroll 8
        for (int k = 0; k < 64; ++k) {
            const float q0 = Qs[rg * 2 + 0][k];
            const float q1 = Qs[rg * 2 + 1][k];
            #pragma unroll
            for (int j = 0; j < 7; ++j) {
                const float w = Ws[k][cg * 7 + j];
                acc0[j] = fmaf(q0, w, acc0[j]);
                acc1[j] = fmaf(q1, w, acc1[j]);
            }
        }
        __syncthreads();
    }

    #pragma unroll
    for (int j = 0; j < 7; ++j) {
        const int col = cg * 7 + j;
        const float bb = bcat[col];
        P[(size_t)(row0 + rg * 2 + 0) * PSTR + col] = acc0[j] + bb;
        P[(size_t)(row0 + rg * 2 + 1) * PSTR + col] = acc1[j] + bb;
    }
}

// ---------------------------------------------------------------------------
// Gather kernel: one WAVE per row (4 rows/block), no cross-wave coupling
// except one barrier. Lane = float4 of channels (64 lanes = 256 ch).
// 128 corner iterations, 8-deep explicit load batches with a per-scalar
// asm liveness hammer so 8 float4 loads are provably in flight.
// ---------------------------------------------------------------------------
__global__ __launch_bounds__(256) void gather_kernel(
    const float* __restrict__ P,      // [BM, 112]
    const float* __restrict__ E,      // [B, H*W, 256]
    const int*   __restrict__ Hp, const int* __restrict__ Wdp,
    ushort* __restrict__ aggb)        // [BM, 256] bf16
{
    const int tid  = threadIdx.x;
    const int wid  = tid >> 6;        // wave in block 0..3
    const int lane = tid & 63;
    const int row  = blockIdx.x * 4 + wid;
    const int b    = row >> 10;       // MQ = 1024

    __shared__ float sW[4][128];
    __shared__ int   sIdx[4][128];    // pixel index in float4 units

    const int Hh = *Hp;
    const int Ww = *Wdp;

    if (lane < 32) {
        const int p = lane;           // point h*4+pt
        const float* Pr = P + (size_t)row * PSTR;
        const float lg = Pr[64 + p];
        float mx = fmaxf(lg, __shfl_xor(lg, 1));
        mx = fmaxf(mx, __shfl_xor(mx, 2));
        const float e = expf(lg - mx);
        float s = e + __shfl_xor(e, 1);
        s += __shfl_xor(s, 2);
        const float aw = e / s * (1.f / NHEAD);

        const float lx = Pr[96] + 0.1f * Pr[p * 2 + 0];
        const float ly = Pr[97] + 0.1f * Pr[p * 2 + 1];
        const float ix = ((lx + 1.f) * (float)Ww - 1.f) * 0.5f;
        const float iy = ((ly + 1.f) * (float)Hh - 1.f) * 0.5f;
        const float x0f = floorf(ix), y0f = floorf(iy);
        const int   x0  = (int)x0f,   y0  = (int)y0f;
        const float wx1 = ix - x0f, wx0 = 1.f - wx1;
        const float wy1 = iy - y0f, wy0 = 1.f - wy1;

        #pragma unroll
        for (int c = 0; c < 4; ++c) {
            const int   xc = x0 + (c & 1);
            const int   yc = y0 + (c >> 1);
            const float wx = (c & 1) ? wx1 : wx0;
            const float wy = (c >> 1) ? wy1 : wy0;
            const bool valid = (xc >= 0) && (xc < Ww) && (yc >= 0) && (yc < Hh);
            const int xi = min(max(xc, 0), Ww - 1);
            const int yi = min(max(yc, 0), Hh - 1);
            sW  [wid][p * 4 + c] = valid ? (wx * wy * aw) : 0.f;
            sIdx[wid][p * 4 + c] = (yi * Ww + xi) * (DIM / 4);
        }
    }
    __syncthreads();

    const float4* __restrict__ Eb4 =
        (const float4*)(E + (size_t)b * (size_t)(Hh * Ww) * DIM);

    float4 acc = make_float4(0.f, 0.f, 0.f, 0.f);
    for (int t = 0; t < 128; t += 8) {
        const float w0 = sW[wid][t + 0]; const int i0 = sIdx[wid][t + 0];
        const float w1 = sW[wid][t + 1]; const int i1 = sIdx[wid][t + 1];
        const float w2 = sW[wid][t + 2]; const int i2 = sIdx[wid][t + 2];
        const float w3 = sW[wid][t + 3]; const int i3 = sIdx[wid][t + 3];
        const float w4 = sW[wid][t + 4]; const int i4 = sIdx[wid][t + 4];
        const float w5 = sW[wid][t + 5]; const int i5 = sIdx[wid][t + 5];
        const float w6 = sW[wid][t + 6]; const int i6 = sIdx[wid][t + 6];
        const float w7 = sW[wid][t + 7]; const int i7 = sIdx[wid][t + 7];

        float4 e0 = Eb4[(size_t)i0 + lane];
        float4 e1 = Eb4[(size_t)i1 + lane];
        float4 e2 = Eb4[(size_t)i2 + lane];
        float4 e3 = Eb4[(size_t)i3 + lane];
        float4 e4 = Eb4[(size_t)i4 + lane];
        float4 e5 = Eb4[(size_t)i5 + lane];
        float4 e6 = Eb4[(size_t)i6 + lane];
        float4 e7 = Eb4[(size_t)i7 + lane];
        // Liveness hammer (per-scalar): force all 8 loads in flight before
        // any FMA consumes them (R5/R6: compiler re-serializes otherwise).
        KEEP4(e0); KEEP4(e1); KEEP4(e2); KEEP4(e3);
        KEEP4(e4); KEEP4(e5); KEEP4(e6); KEEP4(e7);

        acc.x = fmaf(w0, e0.x, acc.x); acc.y = fmaf(w0, e0.y, acc.y);
        acc.z = fmaf(w0, e0.z, acc.z); acc.w = fmaf(w0, e0.w, acc.w);
        acc.x = fmaf(w1, e1.x, acc.x); acc.y = fmaf(w1, e1.y, acc.y);
        acc.z = fmaf(w1, e1.z, acc.z); acc.w = fmaf(w1, e1.w, acc.w);
        acc.x = fmaf(w2, e2.x, acc.x); acc.y = fmaf(w2, e2.y, acc.y);
        acc.z = fmaf(w2, e2.z, acc.z); acc.w = fmaf(w2, e2.w, acc.w);
        acc.x = fmaf(w3, e3.x, acc.x); acc.y = fmaf(w3, e3.y, acc.y);
        acc.z = fmaf(w3, e3.z, acc.z); acc.w = fmaf(w3, e3.w, acc.w);
        acc.x = fmaf(w4, e4.x, acc.x); acc.y = fmaf(w4, e4.y, acc.y);
        acc.z = fmaf(w4, e4.z, acc.z); acc.w = fmaf(w4, e4.w, acc.w);
        acc.x = fmaf(w5, e5.x, acc.x); acc.y = fmaf(w5, e5.y, acc.y);
        acc.z = fmaf(w5, e5.z, acc.z); acc.w = fmaf(w5, e5.w, acc.w);
        acc.x = fmaf(w6, e6.x, acc.x); acc.y = fmaf(w6, e6.y, acc.y);
        acc.z = fmaf(w6, e6.z, acc.z); acc.w = fmaf(w6, e6.w, acc.w);
        acc.x = fmaf(w7, e7.x, acc.x); acc.y = fmaf(w7, e7.y, acc.y);
        acc.z = fmaf(w7, e7.z, acc.z); acc.w = fmaf(w7, e7.w, acc.w);
    }

    ushort4 o;
    o.x = f2bf(acc.x); o.y = f2bf(acc.y);
    o.z = f2bf(acc.z); o.w = f2bf(acc.w);
    *(ushort4*)&aggb[(size_t)row * DIM + lane * 4] = o;
}

// ---------------------------------------------------------------------------
// Tiny kernel: WpT[n][k] = bf16(Wp[k][n]).  (unchanged)
// ---------------------------------------------------------------------------
__global__ __launch_bounds__(256) void wp_convert_kernel(
    const float* __restrict__ Wp, ushort* __restrict__ WpT)
{
    const int k = blockIdx.x;
    const int n = threadIdx.x;
    WpT[(size_t)n * DIM + k] = f2bf(Wp[(size_t)k * DIM + n]);
}

// ---------------------------------------------------------------------------
// Kernel B: out = agg @ Wp + bp via bf16 MFMA (fp32 accumulate). (unchanged)
// ---------------------------------------------------------------------------
__global__ __launch_bounds__(256) void mfma_gemm_kernel(
    const ushort* __restrict__ A,     // [M, 256] bf16
    const ushort* __restrict__ BT,    // [256, 256] bf16 (transposed Wp)
    const float*  __restrict__ bp,    // [256]
    float* __restrict__ out)          // [M, 256]
{
    __shared__ ushort ldsA[64 * 40];
    __shared__ ushort ldsB[64 * 40];

    const int tid  = threadIdx.x;
    const int mb   = blockIdx.x * 64;
    const int nb   = blockIdx.y * 64;
    const int wave = tid >> 6;
    const int lane = tid & 63;
    const int r0   = (wave >> 1) * 32;
    const int c0   = (wave & 1) * 32;
    const int lrow = lane & 15;
    const int kgrp = lane >> 4;

    const int sm = tid >> 2;
    const int sc = (tid & 3) * 8;

    f32x4 acc00 = {0.f, 0.f, 0.f, 0.f};
    f32x4 acc01 = {0.f, 0.f, 0.f, 0.f};
    f32x4 acc10 = {0.f, 0.f, 0.f, 0.f};
    f32x4 acc11 = {0.f, 0.f, 0.f, 0.f};

    for (int kb = 0; kb < DIM; kb += 32) {
        *(uint4*)&ldsA[sm * 40 + sc] =
            *(const uint4*)&A[(size_t)(mb + sm) * DIM + kb + sc];
        *(uint4*)&ldsB[sm * 40 + sc] =
            *(const uint4*)&BT[(size_t)(nb + sm) * DIM + kb + sc];
        __syncthreads();

        const short8 a0 = *(const short8*)&ldsA[(r0 + lrow)      * 40 + kgrp * 8];
        const short8 a1 = *(const short8*)&ldsA[(r0 + 16 + lrow) * 40 + kgrp * 8];
        const short8 b0 = *(const short8*)&ldsB[(c0 + lrow)      * 40 + kgrp * 8];
        const short8 b1 = *(const short8*)&ldsB[(c0 + 16 + lrow) * 40 + kgrp * 8];

        acc00 = __builtin_amdgcn_mfma_f32_16x16x32_bf16(a0, b0, acc00, 0, 0, 0);
        acc01 = __builtin_amdgcn_mfma_f32_16x16x32_bf16(a0, b1, acc01, 0, 0, 0);
        acc10 = __builtin_amdgcn_mfma_f32_16x16x32_bf16(a1, b0, acc10, 0, 0, 0);
        acc11 = __builtin_amdgcn_mfma_f32_16x16x32_bf16(a1, b1, acc11, 0, 0, 0);
        __syncthreads();
    }

    const int orow = mb + r0 + kgrp * 4;
    const int ocol = nb + c0 + lrow;
    const float bp0 = bp[ocol];
    const float bp1 = bp[ocol + 16];
    #pragma unroll
    for (int reg = 0; reg < 4; ++reg) {
        out[(size_t)(orow + reg)      * DIM + ocol]      = acc00[reg] + bp0;
        out[(size_t)(orow + reg)      * DIM + ocol + 16] = acc01[reg] + bp1;
        out[(size_t)(orow + 16 + reg) * DIM + ocol]      = acc10[reg] + bp0;
        out[(size_t)(orow + 16 + reg) * DIM + ocol + 16] = acc11[reg] + bp1;
    }
}

// ---------------------------------------------------------------------------
extern "C" void kernel_launch(void* const* d_in, const int* in_sizes, int n_in,
                              void* d_out, int out_size, void* d_ws, size_t ws_size,
                              hipStream_t stream)
{
    const float* SADQ = (const float*)d_in[0];
    const float* E    = (const float*)d_in[1];
    const float* Wo   = (const float*)d_in[2];
    const float* bo   = (const float*)d_in[3];
    const float* Wa   = (const float*)d_in[4];
    const float* ba   = (const float*)d_in[5];
    const float* Wr   = (const float*)d_in[6];
    const float* br   = (const float*)d_in[7];
    const float* Wp   = (const float*)d_in[8];
    const float* bp   = (const float*)d_in[9];
    const int*   Hp   = (const int*)d_in[10];
    const int*   Wdp  = (const int*)d_in[11];

    const int BM = in_sizes[0] / DIM;          // 8192 rows

    // Workspace layout (bytes):
    //   aggb: [BM][256] bf16   = 4,194,304
    //   WpT : [256][256] bf16  =   131,072
    //   P   : [BM][112] fp32   = 3,670,016
    //   Wcat: [256][112] fp32  =   114,688
    //   bcat: [112] fp32       =       448
    char* ws = (char*)d_ws;
    ushort* aggb = (ushort*)(ws);
    ushort* WpT  = (ushort*)(ws + 4194304);
    float*  P    = (float*) (ws + 4194304 + 131072);
    float*  Wcat = (float*) (ws + 4194304 + 131072 + 3670016);
    float*  bcat = (float*) (ws + 4194304 + 131072 + 3670016 + 114688);
    float*  out  = (float*)d_out;

    wcat_build_kernel<<<DIM, PSTR, 0, stream>>>(Wo, bo, Wa, ba, Wr, br, Wcat, bcat);
    proj_kernel<<<BM / 32, 256, 0, stream>>>(SADQ, Wcat, bcat, P);
    gather_kernel<<<BM / 4, 256, 0, stream>>>(P, E, Hp, Wdp, aggb);
    wp_convert_kernel<<<DIM, 256, 0, stream>>>(Wp, WpT);

    dim3 g2(BM / 64, DIM / 64);
    mfma_gemm_kernel<<<g2, 256, 0, stream>>>(aggb, WpT, bp, out);
}